// Round 4
// baseline (1172.945 us; speedup 1.0000x reference)
//
#include <hip/hip_runtime.h>

#define N_NODES 200000
#define N_EDGES 400000
#define CH 128
#define N_GRAPHS 8192
#define BN_EPS 1e-5f

#define TM 64
#define SCAN_NB ((N_NODES + 1023) / 1024)   // 196 scan blocks

typedef __attribute__((ext_vector_type(8))) short bf16x8;
typedef __attribute__((ext_vector_type(4))) float f32x4;

__device__ __forceinline__ short f2bf(float f) {
    unsigned u = __builtin_bit_cast(unsigned, f);
    u = (u + 0x7FFF + ((u >> 16) & 1)) >> 16;   // RNE
    return (short)u;
}
__device__ __forceinline__ float bf2f(short h) {
    unsigned u = ((unsigned)(unsigned short)h) << 16;
    return __builtin_bit_cast(float, u);
}
// LDS element offset, 16B-unit XOR swizzle (conflict-free b128 column reads)
__device__ __forceinline__ int lds_off(int row, int k) {
    return row * CH + ((((k >> 3) ^ (row & 7)) << 3) | (k & 7));
}

// ---------------- CSR build ----------------

__global__ __launch_bounds__(256) void count_kernel(
    const int* __restrict__ dst, int* __restrict__ deg)
{
    int e = blockIdx.x * blockDim.x + threadIdx.x;
    if (e < N_EDGES) atomicAdd(&deg[dst[e]], 1);
}

__global__ __launch_bounds__(256) void block_sums_kernel(
    const int* __restrict__ deg, int* __restrict__ partial)
{
    __shared__ int s[256];
    int t = threadIdx.x;
    int base = blockIdx.x * 1024 + t * 4;
    int v = 0;
    #pragma unroll
    for (int j = 0; j < 4; ++j) {
        int idx = base + j;
        if (idx < N_NODES) v += deg[idx];
    }
    s[t] = v;
    __syncthreads();
    for (int off = 128; off > 0; off >>= 1) {
        if (t < off) s[t] += s[t + off];
        __syncthreads();
    }
    if (t == 0) partial[blockIdx.x] = s[0];
}

__global__ void scan_partial_kernel(int* __restrict__ partial)
{
    if (threadIdx.x == 0) {
        int run = 0;
        for (int b = 0; b < SCAN_NB; ++b) {
            int v = partial[b];
            partial[b] = run;
            run += v;
        }
    }
}

__global__ __launch_bounds__(256) void scan_final_kernel(
    const int* __restrict__ deg, const int* __restrict__ partial,
    int* __restrict__ row_start)
{
    __shared__ int s[256];
    int t = threadIdx.x;
    int base = blockIdx.x * 1024 + t * 4;
    int v[4];
    int tsum = 0;
    #pragma unroll
    for (int j = 0; j < 4; ++j) {
        int idx = base + j;
        v[j] = (idx < N_NODES) ? deg[idx] : 0;
        tsum += v[j];
    }
    s[t] = tsum;
    __syncthreads();
    for (int off = 1; off < 256; off <<= 1) {
        int x = (t >= off) ? s[t - off] : 0;
        __syncthreads();
        s[t] += x;
        __syncthreads();
    }
    int excl = s[t] - tsum + partial[blockIdx.x];
    #pragma unroll
    for (int j = 0; j < 4; ++j) {
        int idx = base + j;
        if (idx < N_NODES) row_start[idx] = excl;
        excl += v[j];
    }
    if (blockIdx.x == 0 && t == 0) row_start[N_NODES] = N_EDGES;
}

__global__ __launch_bounds__(256) void fill_kernel(
    const int* __restrict__ src, const int* __restrict__ dst,
    const int* __restrict__ row_start, int* __restrict__ cur,
    int* __restrict__ adj)
{
    int e = blockIdx.x * blockDim.x + threadIdx.x;
    if (e >= N_EDGES) return;
    int d = dst[e];
    int ofs = atomicAdd(&cur[d], 1);
    adj[row_start[d] + ofs] = src[e];
}

// ---------------- weight prep: transpose + bf16 hi/lo split + BN fold ----------------
__global__ __launch_bounds__(256) void prep_kernel(
    const float* __restrict__ W1, const float* __restrict__ W2,
    const float* __restrict__ b1, const float* __restrict__ gamma,
    const float* __restrict__ beta, const float* __restrict__ mean,
    const float* __restrict__ var,
    short* __restrict__ w1t_hi, short* __restrict__ w1t_lo,
    short* __restrict__ w2t_hi, short* __restrict__ w2t_lo,
    float* __restrict__ bnA, float* __restrict__ bnB)
{
    int idx = blockIdx.x * 256 + threadIdx.x;
    const float* W = (idx < 16384) ? W1 : W2;
    short* th = (idx < 16384) ? w1t_hi : w2t_hi;
    short* tl = (idx < 16384) ? w1t_lo : w2t_lo;
    int e = idx & 16383;
    int c = e >> 7, k = e & 127;
    float w = W[k * CH + c];
    short hi = f2bf(w);
    th[c * CH + k] = hi;
    tl[c * CH + k] = f2bf(w - bf2f(hi));
    if (idx < CH) {
        float sc = rsqrtf(var[idx] + BN_EPS) * gamma[idx];
        bnA[idx] = sc;
        bnB[idx] = (b1[idx] - mean[idx]) * sc + beta[idx];
    }
}

// ---------------- per-layer kernels ----------------

// hsum[n] = in[n] + sum_{s in adj[n]} in[s]; one wave per node, float2/lane
__global__ __launch_bounds__(256) void gather_kernel(
    const float* __restrict__ in, const int* __restrict__ row_start,
    const int* __restrict__ adj, float* __restrict__ out)
{
    int gid = blockIdx.x * blockDim.x + threadIdx.x;
    int n = gid >> 6;
    int lane = gid & 63;
    if (n >= N_NODES) return;
    float2 acc = ((const float2*)(in + (long)n * CH))[lane];
    int beg = row_start[n];
    int end = row_start[n + 1];
    for (int i = beg; i < end; ++i) {
        int s = adj[i];
        float2 v = ((const float2*)(in + (long)s * CH))[lane];
        acc.x += v.x;
        acc.y += v.y;
    }
    ((float2*)(out + (long)n * CH))[lane] = acc;
}

// Fused GIN MLP via MFMA bf16x3, in place:
//   h = relu( relu(bn(h @ W1 + b1)) @ W2 + b2 )
// 64 rows/block, 4 waves, each wave owns 16 rows x 128 cols.
// (256,2): cap 2 blocks/CU -> ~256 VGPR budget so B-fragments stay in flight.
__global__ __launch_bounds__(256, 2) void mlp_mfma(
    float* __restrict__ h,
    const short* __restrict__ w1t_hi, const short* __restrict__ w1t_lo,
    const short* __restrict__ w2t_hi, const short* __restrict__ w2t_lo,
    const float* __restrict__ bnA, const float* __restrict__ bnB,
    const float* __restrict__ b2)
{
    __shared__ short t_hi[TM * CH];
    __shared__ short t_lo[TM * CH];
    const int tid = threadIdx.x;
    const int w  = tid >> 6;
    const int l  = tid & 63;
    const int lr = l & 15;     // A-row / B-col / C-col within 16-tile
    const int lk = l >> 4;     // k-group (8 elems each)
    const long rowbase = (long)blockIdx.x * TM + w * 16;

    // ---- GEMM1: A straight from global f32 (hi/lo split in-register) ----
    bf16x8 ah[4], al[4];
    #pragma unroll
    for (int ks = 0; ks < 4; ++ks) {
        const float* p = h + (rowbase + lr) * CH + ks * 32 + lk * 8;
        float4 f0 = *(const float4*)p;
        float4 f1 = *(const float4*)(p + 4);
        float fv[8] = {f0.x, f0.y, f0.z, f0.w, f1.x, f1.y, f1.z, f1.w};
        #pragma unroll
        for (int j = 0; j < 8; ++j) {
            short hi = f2bf(fv[j]);
            ah[ks][j] = hi;
            al[ks][j] = f2bf(fv[j] - bf2f(hi));
        }
    }

    f32x4 acc[8];
    #pragma unroll
    for (int ct = 0; ct < 8; ++ct) acc[ct] = (f32x4){0.f, 0.f, 0.f, 0.f};

    // per k-slice: batch all 16 B loads (independent), then 24 MFMAs
    #pragma unroll
    for (int ks = 0; ks < 4; ++ks) {
        bf16x8 bh[8], bl[8];
        #pragma unroll
        for (int ct = 0; ct < 8; ++ct) {
            bh[ct] = *(const bf16x8*)(w1t_hi + (ct * 16 + lr) * CH + ks * 32 + lk * 8);
            bl[ct] = *(const bf16x8*)(w1t_lo + (ct * 16 + lr) * CH + ks * 32 + lk * 8);
        }
        #pragma unroll
        for (int ct = 0; ct < 8; ++ct) {
            acc[ct] = __builtin_amdgcn_mfma_f32_16x16x32_bf16(ah[ks], bh[ct], acc[ct], 0, 0, 0);
            acc[ct] = __builtin_amdgcn_mfma_f32_16x16x32_bf16(ah[ks], bl[ct], acc[ct], 0, 0, 0);
            acc[ct] = __builtin_amdgcn_mfma_f32_16x16x32_bf16(al[ks], bh[ct], acc[ct], 0, 0, 0);
        }
    }

    // ---- BN + ReLU, C-layout -> swizzled LDS (A-layout source for GEMM2) ----
    // C/D mapping (m89): col = lr, row = lk*4 + i
    #pragma unroll
    for (int ct = 0; ct < 8; ++ct) {
        int col = ct * 16 + lr;
        float sA = bnA[col], sB = bnB[col];
        #pragma unroll
        for (int i = 0; i < 4; ++i) {
            int row = w * 16 + lk * 4 + i;
            float t = fmaf(acc[ct][i], sA, sB);
            t = fmaxf(t, 0.f);
            short hi = f2bf(t);
            t_hi[lds_off(row, col)] = hi;
            t_lo[lds_off(row, col)] = f2bf(t - bf2f(hi));
        }
    }
    __syncthreads();

    // ---- GEMM2: A from LDS, B = w2t ----
    bf16x8 a2h[4], a2l[4];
    #pragma unroll
    for (int ks = 0; ks < 4; ++ks) {
        int row = w * 16 + lr;
        int k0 = ks * 32 + lk * 8;
        a2h[ks] = *(const bf16x8*)&t_hi[lds_off(row, k0)];
        a2l[ks] = *(const bf16x8*)&t_lo[lds_off(row, k0)];
    }
    #pragma unroll
    for (int ct = 0; ct < 8; ++ct) acc[ct] = (f32x4){0.f, 0.f, 0.f, 0.f};

    #pragma unroll
    for (int ks = 0; ks < 4; ++ks) {
        bf16x8 bh[8], bl[8];
        #pragma unroll
        for (int ct = 0; ct < 8; ++ct) {
            bh[ct] = *(const bf16x8*)(w2t_hi + (ct * 16 + lr) * CH + ks * 32 + lk * 8);
            bl[ct] = *(const bf16x8*)(w2t_lo + (ct * 16 + lr) * CH + ks * 32 + lk * 8);
        }
        #pragma unroll
        for (int ct = 0; ct < 8; ++ct) {
            acc[ct] = __builtin_amdgcn_mfma_f32_16x16x32_bf16(a2h[ks], bh[ct], acc[ct], 0, 0, 0);
            acc[ct] = __builtin_amdgcn_mfma_f32_16x16x32_bf16(a2h[ks], bl[ct], acc[ct], 0, 0, 0);
            acc[ct] = __builtin_amdgcn_mfma_f32_16x16x32_bf16(a2l[ks], bh[ct], acc[ct], 0, 0, 0);
        }
    }

    // ---- bias + ReLU, store in place ----
    #pragma unroll
    for (int ct = 0; ct < 8; ++ct) {
        int col = ct * 16 + lr;
        float bb = b2[col];
        #pragma unroll
        for (int i = 0; i < 4; ++i) {
            long row = rowbase + lk * 4 + i;
            h[row * CH + col] = fmaxf(acc[ct][i] + bb, 0.f);
        }
    }
}

__global__ void init_out(float* __restrict__ out, const float* __restrict__ lin_b) {
    int i = blockIdx.x * blockDim.x + threadIdx.x;
    if (i < N_GRAPHS) out[i] = lin_b[0];
}

// out[batch[n]] += dot(h[n], lin_w); one wave per node
__global__ __launch_bounds__(256) void pool_kernel(
    const float* __restrict__ h, const int* __restrict__ batch,
    const float* __restrict__ lin_w, float* __restrict__ out)
{
    int gid = blockIdx.x * blockDim.x + threadIdx.x;
    int n = gid >> 6;
    int lane = gid & 63;
    if (n >= N_NODES) return;
    float2 v = ((const float2*)(h + (long)n * CH))[lane];
    float2 w = ((const float2*)lin_w)[lane];
    float s = v.x * w.x + v.y * w.y;
    #pragma unroll
    for (int off = 32; off > 0; off >>= 1) s += __shfl_down(s, off);
    if (lane == 0) atomicAdd(&out[batch[n]], s);
}

extern "C" void kernel_launch(void* const* d_in, const int* in_sizes, int n_in,
                              void* d_out, int out_size, void* d_ws, size_t ws_size,
                              hipStream_t stream) {
    const float* x     = (const float*)d_in[0];
    const int*   ei    = (const int*)d_in[1];
    const int*   batch = (const int*)d_in[2];
    const float* lin_w = (const float*)d_in[3];
    const float* lin_b = (const float*)d_in[4];
    const float* P[3][8];
    for (int l = 0; l < 3; ++l)
        for (int j = 0; j < 8; ++j)
            P[l][j] = (const float*)d_in[5 + l * 8 + j];
    // P[l]: 0=w1 1=b1 2=gamma 3=beta 4=mean 5=var 6=w2 7=b2

    const int* src = ei;            // edge_index[0]
    const int* dst = ei + N_EDGES;  // edge_index[1]

    // workspace layout
    float* buf0 = (float*)d_ws;
    float* buf1 = buf0 + (size_t)N_NODES * CH;
    int* deg       = (int*)(buf1 + (size_t)N_NODES * CH);
    int* row_start = deg + N_NODES;
    int* adj       = row_start + N_NODES + 1;
    int* partial   = adj + N_EDGES;
    short* wts     = (short*)(partial + SCAN_NB + 64);
    short* w1t_hi[3]; short* w1t_lo[3]; short* w2t_hi[3]; short* w2t_lo[3];
    float* bnA[3]; float* bnB[3];
    {
        short* p = wts;
        for (int l = 0; l < 3; ++l) {
            w1t_hi[l] = p; p += 16384;
            w1t_lo[l] = p; p += 16384;
            w2t_hi[l] = p; p += 16384;
            w2t_lo[l] = p; p += 16384;
            bnA[l] = (float*)p; p += 256;   // 128 floats
            bnB[l] = (float*)p; p += 256;
        }
    }

    // ---- weight prep ----
    for (int l = 0; l < 3; ++l)
        prep_kernel<<<128, 256, 0, stream>>>(
            P[l][0], P[l][6], P[l][1], P[l][2], P[l][3], P[l][4], P[l][5],
            w1t_hi[l], w1t_lo[l], w2t_hi[l], w2t_lo[l], bnA[l], bnB[l]);

    // ---- CSR build ----
    hipMemsetAsync(deg, 0, N_NODES * sizeof(int), stream);
    count_kernel<<<(N_EDGES + 255) / 256, 256, 0, stream>>>(dst, deg);
    block_sums_kernel<<<SCAN_NB, 256, 0, stream>>>(deg, partial);
    scan_partial_kernel<<<1, 64, 0, stream>>>(partial);
    scan_final_kernel<<<SCAN_NB, 256, 0, stream>>>(deg, partial, row_start);
    hipMemsetAsync(deg, 0, N_NODES * sizeof(int), stream);  // reuse as cursor
    fill_kernel<<<(N_EDGES + 255) / 256, 256, 0, stream>>>(src, dst, row_start, deg, adj);

    // ---- 3 GIN layers: gather (ping-pong) + in-place MFMA MLP ----
    const float* in_l[3] = {x,    buf0, buf1};
    float*       gout[3] = {buf0, buf1, buf0};

    for (int l = 0; l < 3; ++l) {
        gather_kernel<<<(N_NODES * 64) / 256, 256, 0, stream>>>(
            in_l[l], row_start, adj, gout[l]);
        mlp_mfma<<<N_NODES / TM, 256, 0, stream>>>(
            gout[l],
            w1t_hi[l], w1t_lo[l], w2t_hi[l], w2t_lo[l],
            bnA[l], bnB[l], P[l][7]);
    }

    // ---- pool + final linear (OUT_CH == 1) ----
    init_out<<<(N_GRAPHS + 255) / 256, 256, 0, stream>>>((float*)d_out, lin_b);
    pool_kernel<<<(N_NODES * 64) / 256, 256, 0, stream>>>(buf0, batch, lin_w, (float*)d_out);
}

// Round 5
// 859.307 us; speedup vs baseline: 1.3650x; 1.3650x over previous
//
#include <hip/hip_runtime.h>
#include <stdint.h>

#define N_NODES 200000
#define N_EDGES 400000
#define CH 128
#define N_GRAPHS 8192
#define BN_EPS 1e-5f

#define TM 128
#define THREADS 512
#define SCAN_NB ((N_NODES + 1023) / 1024)   // 196 scan blocks

typedef __attribute__((ext_vector_type(8))) short bf16x8;
typedef __attribute__((ext_vector_type(4))) float f32x4;

__device__ __forceinline__ short f2bf(float f) {
    unsigned u = __builtin_bit_cast(unsigned, f);
    u = (u + 0x7FFF + ((u >> 16) & 1)) >> 16;   // RNE
    return (short)u;
}
__device__ __forceinline__ float bf2f(short h) {
    unsigned u = ((unsigned)(unsigned short)h) << 16;
    return __builtin_bit_cast(float, u);
}
// swizzled short index inside a [128][128] tile: 16B-unit XOR by (row&7)
__device__ __forceinline__ int swz(int row, int k) {
    return row * CH + ((((k >> 3) ^ (row & 7)) << 3) | (k & 7));
}

// ---------------- CSR build ----------------

__global__ __launch_bounds__(256) void count_kernel(
    const int* __restrict__ dst, int* __restrict__ deg)
{
    int e = blockIdx.x * blockDim.x + threadIdx.x;
    if (e < N_EDGES) atomicAdd(&deg[dst[e]], 1);
}

__global__ __launch_bounds__(256) void block_sums_kernel(
    const int* __restrict__ deg, int* __restrict__ partial)
{
    __shared__ int s[256];
    int t = threadIdx.x;
    int base = blockIdx.x * 1024 + t * 4;
    int v = 0;
    #pragma unroll
    for (int j = 0; j < 4; ++j) {
        int idx = base + j;
        if (idx < N_NODES) v += deg[idx];
    }
    s[t] = v;
    __syncthreads();
    for (int off = 128; off > 0; off >>= 1) {
        if (t < off) s[t] += s[t + off];
        __syncthreads();
    }
    if (t == 0) partial[blockIdx.x] = s[0];
}

__global__ void scan_partial_kernel(int* __restrict__ partial)
{
    if (threadIdx.x == 0) {
        int run = 0;
        for (int b = 0; b < SCAN_NB; ++b) {
            int v = partial[b];
            partial[b] = run;
            run += v;
        }
    }
}

__global__ __launch_bounds__(256) void scan_final_kernel(
    const int* __restrict__ deg, const int* __restrict__ partial,
    int* __restrict__ row_start)
{
    __shared__ int s[256];
    int t = threadIdx.x;
    int base = blockIdx.x * 1024 + t * 4;
    int v[4];
    int tsum = 0;
    #pragma unroll
    for (int j = 0; j < 4; ++j) {
        int idx = base + j;
        v[j] = (idx < N_NODES) ? deg[idx] : 0;
        tsum += v[j];
    }
    s[t] = tsum;
    __syncthreads();
    for (int off = 1; off < 256; off <<= 1) {
        int x = (t >= off) ? s[t - off] : 0;
        __syncthreads();
        s[t] += x;
        __syncthreads();
    }
    int excl = s[t] - tsum + partial[blockIdx.x];
    #pragma unroll
    for (int j = 0; j < 4; ++j) {
        int idx = base + j;
        if (idx < N_NODES) row_start[idx] = excl;
        excl += v[j];
    }
    if (blockIdx.x == 0 && t == 0) row_start[N_NODES] = N_EDGES;
}

__global__ __launch_bounds__(256) void fill_kernel(
    const int* __restrict__ src, const int* __restrict__ dst,
    const int* __restrict__ row_start, int* __restrict__ cur,
    int* __restrict__ adj)
{
    int e = blockIdx.x * blockDim.x + threadIdx.x;
    if (e >= N_EDGES) return;
    int d = dst[e];
    int ofs = atomicAdd(&cur[d], 1);
    adj[row_start[d] + ofs] = src[e];
}

// ------- weight prep: transpose + bf16 hi/lo split + XOR-swizzle + BN fold -------
// wg layout (32768 shorts): [0:16384) = hi swizzled, [16384:32768) = lo swizzled.
// Exact LDS image -> staging is a linear copy.
__global__ __launch_bounds__(256) void prep_kernel(
    const float* __restrict__ W1, const float* __restrict__ W2,
    const float* __restrict__ b1, const float* __restrict__ gamma,
    const float* __restrict__ beta, const float* __restrict__ mean,
    const float* __restrict__ var,
    short* __restrict__ wg1, short* __restrict__ wg2,
    float* __restrict__ bnA, float* __restrict__ bnB)
{
    int idx = blockIdx.x * 256 + threadIdx.x;   // 0..32767
    const float* W = (idx < 16384) ? W1 : W2;
    short* wg = (idx < 16384) ? wg1 : wg2;
    int e = idx & 16383;
    int c = e >> 7, k = e & 127;                 // c = output col, k = input dim
    float v = W[k * CH + c];
    short hi = f2bf(v);
    int six = swz(c, k);
    wg[six] = hi;
    wg[16384 + six] = f2bf(v - bf2f(hi));
    if (idx < CH) {
        float sc = rsqrtf(var[idx] + BN_EPS) * gamma[idx];
        bnA[idx] = sc;
        bnB[idx] = (b1[idx] - mean[idx]) * sc + beta[idx];
    }
}

// ---------------- per-layer kernels ----------------

// hsum[n] = in[n] + sum_{s in adj[n]} in[s]; one wave per node, float2/lane
__global__ __launch_bounds__(256) void gather_kernel(
    const float* __restrict__ in, const int* __restrict__ row_start,
    const int* __restrict__ adj, float* __restrict__ out)
{
    int gid = blockIdx.x * blockDim.x + threadIdx.x;
    int n = gid >> 6;
    int lane = gid & 63;
    if (n >= N_NODES) return;
    float2 acc = ((const float2*)(in + (long)n * CH))[lane];
    int beg = row_start[n];
    int end = row_start[n + 1];
    for (int i = beg; i < end; ++i) {
        int s = adj[i];
        float2 v = ((const float2*)(in + (long)s * CH))[lane];
        acc.x += v.x;
        acc.y += v.y;
    }
    ((float2*)(out + (long)n * CH))[lane] = acc;
}

// Fused GIN MLP via MFMA bf16x3, in place, LDS-staged weights.
// 512 threads = 8 waves; wave (wr,wc) owns rows [wr*32, wr*32+32) x cols [wc*64, wc*64+64).
// LDS: Wl = current GEMM's weights (hi|lo, swizzled), Tl = inter-GEMM activations.
__global__ __launch_bounds__(THREADS, 2) void mlp_mfma(
    float* __restrict__ h,
    const short* __restrict__ wg1, const short* __restrict__ wg2,
    const float* __restrict__ bnA, const float* __restrict__ bnB,
    const float* __restrict__ b2)
{
    __shared__ __align__(16) short Wl[32768];   // 64 KB
    __shared__ __align__(16) short Tl[32768];   // 64 KB

    const int tid = threadIdx.x;
    const int w  = tid >> 6;
    const int l  = tid & 63;
    const int lr = l & 15;     // row/col within 16-tile
    const int lk = l >> 4;     // k-group (8 elems)
    const int wr = w >> 1;     // 0..3
    const int wc = w & 1;      // 0..1
    const long rowbase = (long)blockIdx.x * TM;

    // ---- A loads (f32) for this wave's 32 rows; issue before staging barrier ----
    float4 af[2][8];
    #pragma unroll
    for (int mi = 0; mi < 2; ++mi) {
        long row = rowbase + wr * 32 + mi * 16 + lr;
        if (row < N_NODES) {
            const float* ap = h + row * CH + lk * 8;
            #pragma unroll
            for (int ks = 0; ks < 4; ++ks) {
                af[mi][2 * ks]     = *(const float4*)(ap + ks * 32);
                af[mi][2 * ks + 1] = *(const float4*)(ap + ks * 32 + 4);
            }
        } else {
            #pragma unroll
            for (int j = 0; j < 8; ++j) af[mi][j] = make_float4(0.f, 0.f, 0.f, 0.f);
        }
    }

    // ---- stage W1 into LDS (linear copy of pre-swizzled image) ----
    #pragma unroll
    for (int it = 0; it < 8; ++it) {
        int u = it * THREADS + tid;
        *(bf16x8*)&Wl[u * 8] = *(const bf16x8*)&wg1[u * 8];
    }
    __syncthreads();

    // ---- convert A to bf16 hi/lo ----
    bf16x8 ah[2][4], al[2][4];
    #pragma unroll
    for (int mi = 0; mi < 2; ++mi)
        #pragma unroll
        for (int ks = 0; ks < 4; ++ks) {
            float fv[8] = {af[mi][2*ks].x, af[mi][2*ks].y, af[mi][2*ks].z, af[mi][2*ks].w,
                           af[mi][2*ks+1].x, af[mi][2*ks+1].y, af[mi][2*ks+1].z, af[mi][2*ks+1].w};
            #pragma unroll
            for (int j = 0; j < 8; ++j) {
                short hi = f2bf(fv[j]);
                ah[mi][ks][j] = hi;
                al[mi][ks][j] = f2bf(fv[j] - bf2f(hi));
            }
        }

    f32x4 acc[2][4];
    #pragma unroll
    for (int mi = 0; mi < 2; ++mi)
        #pragma unroll
        for (int ct = 0; ct < 4; ++ct) acc[mi][ct] = (f32x4){0.f, 0.f, 0.f, 0.f};

    // ---- GEMM1: B from LDS ----
    #pragma unroll
    for (int ks = 0; ks < 4; ++ks) {
        bf16x8 bh[4], bl[4];
        #pragma unroll
        for (int ct = 0; ct < 4; ++ct) {
            int r = wc * 64 + ct * 16 + lr;
            int off = (r * 16 + ((ks * 4 + lk) ^ (r & 7))) * 8;
            bh[ct] = *(const bf16x8*)&Wl[off];
            bl[ct] = *(const bf16x8*)&Wl[16384 + off];
        }
        #pragma unroll
        for (int ct = 0; ct < 4; ++ct)
            #pragma unroll
            for (int mi = 0; mi < 2; ++mi) {
                acc[mi][ct] = __builtin_amdgcn_mfma_f32_16x16x32_bf16(ah[mi][ks], bh[ct], acc[mi][ct], 0, 0, 0);
                acc[mi][ct] = __builtin_amdgcn_mfma_f32_16x16x32_bf16(ah[mi][ks], bl[ct], acc[mi][ct], 0, 0, 0);
                acc[mi][ct] = __builtin_amdgcn_mfma_f32_16x16x32_bf16(al[mi][ks], bh[ct], acc[mi][ct], 0, 0, 0);
            }
    }

    // ---- prefetch W2 to regs (issue-early), write after barrier ----
    bf16x8 wtmp[8];
    #pragma unroll
    for (int it = 0; it < 8; ++it)
        wtmp[it] = *(const bf16x8*)&wg2[(it * THREADS + tid) * 8];

    __syncthreads();   // all GEMM1 Wl reads done

    #pragma unroll
    for (int it = 0; it < 8; ++it)
        *(bf16x8*)&Wl[(it * THREADS + tid) * 8] = wtmp[it];

    // ---- BN + ReLU, C-layout -> swizzled Tl ----
    // C/D mapping: col = lr, row = lk*4 + i (within 16x16 tile)
    #pragma unroll
    for (int ct = 0; ct < 4; ++ct) {
        int col = wc * 64 + ct * 16 + lr;
        float sA = bnA[col], sB = bnB[col];
        #pragma unroll
        for (int mi = 0; mi < 2; ++mi)
            #pragma unroll
            for (int i = 0; i < 4; ++i) {
                int row = wr * 32 + mi * 16 + lk * 4 + i;
                float t = fmaxf(fmaf(acc[mi][ct][i], sA, sB), 0.f);
                short hi = f2bf(t);
                int tix = swz(row, col);
                Tl[tix] = hi;
                Tl[16384 + tix] = f2bf(t - bf2f(hi));
            }
    }
    __syncthreads();

    // ---- GEMM2: A from Tl (own 32 rows), B from Wl ----
    bf16x8 a2h[2][4], a2l[2][4];
    #pragma unroll
    for (int mi = 0; mi < 2; ++mi) {
        int arow = wr * 32 + mi * 16 + lr;
        #pragma unroll
        for (int ks = 0; ks < 4; ++ks) {
            int tix = (arow * 16 + ((ks * 4 + lk) ^ (arow & 7))) * 8;
            a2h[mi][ks] = *(const bf16x8*)&Tl[tix];
            a2l[mi][ks] = *(const bf16x8*)&Tl[16384 + tix];
        }
    }
    #pragma unroll
    for (int mi = 0; mi < 2; ++mi)
        #pragma unroll
        for (int ct = 0; ct < 4; ++ct) acc[mi][ct] = (f32x4){0.f, 0.f, 0.f, 0.f};

    #pragma unroll
    for (int ks = 0; ks < 4; ++ks) {
        bf16x8 bh[4], bl[4];
        #pragma unroll
        for (int ct = 0; ct < 4; ++ct) {
            int r = wc * 64 + ct * 16 + lr;
            int off = (r * 16 + ((ks * 4 + lk) ^ (r & 7))) * 8;
            bh[ct] = *(const bf16x8*)&Wl[off];
            bl[ct] = *(const bf16x8*)&Wl[16384 + off];
        }
        #pragma unroll
        for (int ct = 0; ct < 4; ++ct)
            #pragma unroll
            for (int mi = 0; mi < 2; ++mi) {
                acc[mi][ct] = __builtin_amdgcn_mfma_f32_16x16x32_bf16(a2h[mi][ks], bh[ct], acc[mi][ct], 0, 0, 0);
                acc[mi][ct] = __builtin_amdgcn_mfma_f32_16x16x32_bf16(a2h[mi][ks], bl[ct], acc[mi][ct], 0, 0, 0);
                acc[mi][ct] = __builtin_amdgcn_mfma_f32_16x16x32_bf16(a2l[mi][ks], bh[ct], acc[mi][ct], 0, 0, 0);
            }
    }

    // ---- bias + ReLU, store in place (guarded) ----
    #pragma unroll
    for (int ct = 0; ct < 4; ++ct) {
        int col = wc * 64 + ct * 16 + lr;
        float bb = b2[col];
        #pragma unroll
        for (int mi = 0; mi < 2; ++mi)
            #pragma unroll
            for (int i = 0; i < 4; ++i) {
                long row = rowbase + wr * 32 + mi * 16 + lk * 4 + i;
                if (row < N_NODES)
                    h[row * CH + col] = fmaxf(acc[mi][ct][i] + bb, 0.f);
            }
    }
}

__global__ void init_out(float* __restrict__ out, const float* __restrict__ lin_b) {
    int i = blockIdx.x * blockDim.x + threadIdx.x;
    if (i < N_GRAPHS) out[i] = lin_b[0];
}

// out[batch[n]] += dot(h[n], lin_w); one wave per node
__global__ __launch_bounds__(256) void pool_kernel(
    const float* __restrict__ h, const int* __restrict__ batch,
    const float* __restrict__ lin_w, float* __restrict__ out)
{
    int gid = blockIdx.x * blockDim.x + threadIdx.x;
    int n = gid >> 6;
    int lane = gid & 63;
    if (n >= N_NODES) return;
    float2 v = ((const float2*)(h + (long)n * CH))[lane];
    float2 w = ((const float2*)lin_w)[lane];
    float s = v.x * w.x + v.y * w.y;
    #pragma unroll
    for (int off = 32; off > 0; off >>= 1) s += __shfl_down(s, off);
    if (lane == 0) atomicAdd(&out[batch[n]], s);
}

extern "C" void kernel_launch(void* const* d_in, const int* in_sizes, int n_in,
                              void* d_out, int out_size, void* d_ws, size_t ws_size,
                              hipStream_t stream) {
    const float* x     = (const float*)d_in[0];
    const int*   ei    = (const int*)d_in[1];
    const int*   batch = (const int*)d_in[2];
    const float* lin_w = (const float*)d_in[3];
    const float* lin_b = (const float*)d_in[4];
    const float* P[3][8];
    for (int l = 0; l < 3; ++l)
        for (int j = 0; j < 8; ++j)
            P[l][j] = (const float*)d_in[5 + l * 8 + j];
    // P[l]: 0=w1 1=b1 2=gamma 3=beta 4=mean 5=var 6=w2 7=b2

    const int* src = ei;            // edge_index[0]
    const int* dst = ei + N_EDGES;  // edge_index[1]

    // workspace layout
    float* buf0 = (float*)d_ws;
    float* buf1 = buf0 + (size_t)N_NODES * CH;
    int* deg       = (int*)(buf1 + (size_t)N_NODES * CH);
    int* row_start = deg + N_NODES;
    int* adj       = row_start + N_NODES + 1;
    int* partial   = adj + N_EDGES;
    // 256B-align the weight area (row_start's odd length skews alignment)
    short* wts = (short*)(((uintptr_t)(partial + SCAN_NB) + 255) & ~(uintptr_t)255);
    short* wg1[3]; short* wg2[3];
    float* bnA[3]; float* bnB[3];
    {
        short* p = wts;
        for (int l = 0; l < 3; ++l) {
            wg1[l] = p; p += 32768;
            wg2[l] = p; p += 32768;
            bnA[l] = (float*)p; p += 256;   // 128 floats
            bnB[l] = (float*)p; p += 256;
        }
    }

    // ---- weight prep ----
    for (int l = 0; l < 3; ++l)
        prep_kernel<<<128, 256, 0, stream>>>(
            P[l][0], P[l][6], P[l][1], P[l][2], P[l][3], P[l][4], P[l][5],
            wg1[l], wg2[l], bnA[l], bnB[l]);

    // ---- CSR build ----
    hipMemsetAsync(deg, 0, N_NODES * sizeof(int), stream);
    count_kernel<<<(N_EDGES + 255) / 256, 256, 0, stream>>>(dst, deg);
    block_sums_kernel<<<SCAN_NB, 256, 0, stream>>>(deg, partial);
    scan_partial_kernel<<<1, 64, 0, stream>>>(partial);
    scan_final_kernel<<<SCAN_NB, 256, 0, stream>>>(deg, partial, row_start);
    hipMemsetAsync(deg, 0, N_NODES * sizeof(int), stream);  // reuse as cursor
    fill_kernel<<<(N_EDGES + 255) / 256, 256, 0, stream>>>(src, dst, row_start, deg, adj);

    // ---- 3 GIN layers: gather (ping-pong) + in-place MFMA MLP ----
    const float* in_l[3] = {x,    buf0, buf1};
    float*       gout[3] = {buf0, buf1, buf0};

    for (int l = 0; l < 3; ++l) {
        gather_kernel<<<(N_NODES * 64) / 256, 256, 0, stream>>>(
            in_l[l], row_start, adj, gout[l]);
        mlp_mfma<<<(N_NODES + TM - 1) / TM, THREADS, 0, stream>>>(
            gout[l], wg1[l], wg2[l], bnA[l], bnB[l], P[l][7]);
    }

    // ---- pool + final linear (OUT_CH == 1) ----
    init_out<<<(N_GRAPHS + 255) / 256, 256, 0, stream>>>((float*)d_out, lin_b);
    pool_kernel<<<(N_NODES * 64) / 256, 256, 0, stream>>>(buf0, batch, lin_w, (float*)d_out);
}

// Round 7
// 636.752 us; speedup vs baseline: 1.8421x; 1.3495x over previous
//
#include <hip/hip_runtime.h>
#include <stdint.h>

#define N_NODES 200000
#define N_EDGES 400000
#define CH 128
#define N_GRAPHS 8192
#define BN_EPS 1e-5f

#define THREADS 512
#define GRID 256
#define NT 1563                 // ceil(200000 / 128)
#define SCAN_NB ((N_NODES + 1023) / 1024)

typedef __attribute__((ext_vector_type(8))) short bf16x8;
typedef __attribute__((ext_vector_type(4))) float f32x4;
typedef __attribute__((ext_vector_type(4))) unsigned u32x4;

__device__ __forceinline__ short f2bf(float f) {
    unsigned u = __builtin_bit_cast(unsigned, f);
    u = (u + 0x7FFF + ((u >> 16) & 1)) >> 16;   // RNE
    return (short)u;
}
__device__ __forceinline__ float bf2f(short h) {
    unsigned u = ((unsigned)(unsigned short)h) << 16;
    return __builtin_bit_cast(float, u);
}
// W-plane swizzle: 16B-unit XOR by (row&7); row-major [128][128] shorts
__device__ __forceinline__ int swz(int row, int k) {
    return row * CH + ((((k >> 3) ^ (row & 7)) << 3) | (k & 7));
}

// ---------------- CSR build ----------------

__global__ __launch_bounds__(256) void count_kernel(
    const int* __restrict__ dst, int* __restrict__ deg)
{
    int e = blockIdx.x * blockDim.x + threadIdx.x;
    if (e < N_EDGES) atomicAdd(&deg[dst[e]], 1);
}

__global__ __launch_bounds__(256) void block_sums_kernel(
    const int* __restrict__ deg, int* __restrict__ partial)
{
    __shared__ int s[256];
    int t = threadIdx.x;
    int base = blockIdx.x * 1024 + t * 4;
    int v = 0;
    #pragma unroll
    for (int j = 0; j < 4; ++j) {
        int idx = base + j;
        if (idx < N_NODES) v += deg[idx];
    }
    s[t] = v;
    __syncthreads();
    for (int off = 128; off > 0; off >>= 1) {
        if (t < off) s[t] += s[t + off];
        __syncthreads();
    }
    if (t == 0) partial[blockIdx.x] = s[0];
}

__global__ void scan_partial_kernel(int* __restrict__ partial)
{
    if (threadIdx.x == 0) {
        int run = 0;
        for (int b = 0; b < SCAN_NB; ++b) {
            int v = partial[b];
            partial[b] = run;
            run += v;
        }
    }
}

__global__ __launch_bounds__(256) void scan_final_kernel(
    const int* __restrict__ deg, const int* __restrict__ partial,
    int* __restrict__ row_start)
{
    __shared__ int s[256];
    int t = threadIdx.x;
    int base = blockIdx.x * 1024 + t * 4;
    int v[4];
    int tsum = 0;
    #pragma unroll
    for (int j = 0; j < 4; ++j) {
        int idx = base + j;
        v[j] = (idx < N_NODES) ? deg[idx] : 0;
        tsum += v[j];
    }
    s[t] = tsum;
    __syncthreads();
    for (int off = 1; off < 256; off <<= 1) {
        int x = (t >= off) ? s[t - off] : 0;
        __syncthreads();
        s[t] += x;
        __syncthreads();
    }
    int excl = s[t] - tsum + partial[blockIdx.x];
    #pragma unroll
    for (int j = 0; j < 4; ++j) {
        int idx = base + j;
        if (idx < N_NODES) row_start[idx] = excl;
        excl += v[j];
    }
    if (blockIdx.x == 0 && t == 0) row_start[N_NODES] = N_EDGES;
}

__global__ __launch_bounds__(256) void fill_kernel(
    const int* __restrict__ src, const int* __restrict__ dst,
    const int* __restrict__ row_start, int* __restrict__ cur,
    int* __restrict__ adj)
{
    int e = blockIdx.x * blockDim.x + threadIdx.x;
    if (e >= N_EDGES) return;
    int d = dst[e];
    int ofs = atomicAdd(&cur[d], 1);
    adj[row_start[d] + ofs] = src[e];
}

// ------- weight prep: transpose + bf16 hi/lo split + XOR-swizzle + BN fold -------
// wg (65536 shorts): W1hi[16384] | W1lo | W2hi | W2lo, all transposed+swizzled.
__global__ __launch_bounds__(256) void prep_kernel(
    const float* __restrict__ W1, const float* __restrict__ W2,
    const float* __restrict__ b1, const float* __restrict__ gamma,
    const float* __restrict__ beta, const float* __restrict__ mean,
    const float* __restrict__ var,
    short* __restrict__ wg,
    float* __restrict__ bnA, float* __restrict__ bnB)
{
    int idx = blockIdx.x * 256 + threadIdx.x;   // 0..32767
    const float* W = (idx < 16384) ? W1 : W2;
    int base = (idx < 16384) ? 0 : 32768;
    int e = idx & 16383;
    int c = e >> 7, k = e & 127;                 // c = output col, k = input dim
    float v = W[k * CH + c];
    short hi = f2bf(v);
    int six = swz(c, k);
    wg[base + six] = hi;
    wg[base + 16384 + six] = f2bf(v - bf2f(hi));
    if (idx < CH) {
        float sc = rsqrtf(var[idx] + BN_EPS) * gamma[idx];
        bnA[idx] = sc;
        bnB[idx] = (b1[idx] - mean[idx]) * sc + beta[idx];
    }
}

// ---------------- fused GIN layer ----------------
// out = relu( relu(bn((in[n]+sum_adj in) @ W1 + b1)) @ W2 + b2 )
// Persistent: 256 blocks x 512 thr. All 4 weight planes staged once (128 KB).
// Wave owns 16 rows x 128 cols; GEMM1->GEMM2 transpose via 2KB wave-private
// LDS chunk per 32-channel k-slice -> no barriers in the tile loop.
__global__ __launch_bounds__(THREADS) void gin_layer(
    const float* __restrict__ in, float* __restrict__ out,
    const int* __restrict__ row_start, const int* __restrict__ adj,
    const short* __restrict__ wg,
    const float* __restrict__ bnA, const float* __restrict__ bnB,
    const float* __restrict__ b2)
{
    __shared__ __align__(16) short Wl[65536];      // 128 KB: W1hi|W1lo|W2hi|W2lo
    __shared__ __align__(16) unsigned Tl[4096];    // 16 KB: 8 waves x [16][32] u32

    const int tid = threadIdx.x;
    const int w  = tid >> 6;
    const int l  = tid & 63;
    const int lr = l & 15;
    const int lk = l >> 4;

    // ---- stage all weight planes once ----
    #pragma unroll
    for (int it = 0; it < 16; ++it) {
        int u = it * THREADS + tid;
        *(bf16x8*)&Wl[u * 8] = *(const bf16x8*)&wg[u * 8];
    }
    __syncthreads();

    unsigned* tw = Tl + w * 512;     // wave-private [16][32] u32 chunk

    // per-lane channel constants (channel = ct*16+lr)
    float sA[8], sB[8], b2c[8];
    #pragma unroll
    for (int ct = 0; ct < 8; ++ct) {
        int hid = ct * 16 + lr;
        sA[ct] = bnA[hid];
        sB[ct] = bnB[hid];
        b2c[ct] = b2[hid];
    }

    for (int tile = blockIdx.x; tile < NT; tile += GRID) {
        const long n = (long)tile * 128 + w * 16 + lr;   // lane's node row
        const bool valid = (n < N_NODES);

        // ---- fused gather: av = in[n] + sum_{s in adj[n]} in[s] (f32) ----
        float av[4][8];
        #pragma unroll
        for (int ks = 0; ks < 4; ++ks)
            #pragma unroll
            for (int j = 0; j < 8; ++j) av[ks][j] = 0.f;

        if (valid) {
            const float* rp = in + n * CH + lk * 8;
            #pragma unroll
            for (int ks = 0; ks < 4; ++ks) {
                float4 a0 = *(const float4*)(rp + ks * 32);
                float4 a1 = *(const float4*)(rp + ks * 32 + 4);
                av[ks][0] = a0.x; av[ks][1] = a0.y; av[ks][2] = a0.z; av[ks][3] = a0.w;
                av[ks][4] = a1.x; av[ks][5] = a1.y; av[ks][6] = a1.z; av[ks][7] = a1.w;
            }
            int beg = row_start[n];
            int end = row_start[n + 1];
            for (int i = beg; i < end; ++i) {
                const float* sp = in + (long)adj[i] * CH + lk * 8;
                #pragma unroll
                for (int ks = 0; ks < 4; ++ks) {
                    float4 a0 = *(const float4*)(sp + ks * 32);
                    float4 a1 = *(const float4*)(sp + ks * 32 + 4);
                    av[ks][0] += a0.x; av[ks][1] += a0.y; av[ks][2] += a0.z; av[ks][3] += a0.w;
                    av[ks][4] += a1.x; av[ks][5] += a1.y; av[ks][6] += a1.z; av[ks][7] += a1.w;
                }
            }
        }

        // ---- split A to hi(trunc)/lo(RNE) bf16 ----
        bf16x8 ah[4], al[4];
        #pragma unroll
        for (int ks = 0; ks < 4; ++ks)
            #pragma unroll
            for (int j = 0; j < 8; ++j) {
                float v = av[ks][j];
                unsigned u = __builtin_bit_cast(unsigned, v);
                ah[ks][j] = (short)(u >> 16);
                al[ks][j] = f2bf(v - __builtin_bit_cast(float, u & 0xFFFF0000u));
            }

        f32x4 acc2[8];
        #pragma unroll
        for (int ct = 0; ct < 8; ++ct) acc2[ct] = (f32x4){0.f, 0.f, 0.f, 0.f};

        // ---- per 32-channel chunk: GEMM1 -> T chunk -> GEMM2 partial ----
        #pragma unroll
        for (int ks2 = 0; ks2 < 4; ++ks2) {
            // GEMM1 chunk: T cols ks2*32 .. +31 (ct = 2*ks2, 2*ks2+1), bf16x3
            f32x4 c1[2];
            c1[0] = (f32x4){0.f, 0.f, 0.f, 0.f};
            c1[1] = (f32x4){0.f, 0.f, 0.f, 0.f};
            #pragma unroll
            for (int ksA = 0; ksA < 4; ++ksA) {
                #pragma unroll
                for (int ctl = 0; ctl < 2; ++ctl) {
                    int r = (ks2 * 2 + ctl) * 16 + lr;
                    int off = r * 128 + (((ksA * 4 + lk) ^ (r & 7)) << 3);
                    bf16x8 bh = *(const bf16x8*)&Wl[off];            // W1hi
                    bf16x8 bl = *(const bf16x8*)&Wl[16384 + off];    // W1lo
                    c1[ctl] = __builtin_amdgcn_mfma_f32_16x16x32_bf16(ah[ksA], bh, c1[ctl], 0, 0, 0);
                    c1[ctl] = __builtin_amdgcn_mfma_f32_16x16x32_bf16(al[ksA], bh, c1[ctl], 0, 0, 0);
                    c1[ctl] = __builtin_amdgcn_mfma_f32_16x16x32_bf16(ah[ksA], bl, c1[ctl], 0, 0, 0);
                }
            }

            // BN+ReLU, split, pack (hi,lo) -> wave-private swizzled chunk
            // C layout: col = lr, local row = lk*4+i
            #pragma unroll
            for (int ctl = 0; ctl < 2; ++ctl) {
                int ct = ks2 * 2 + ctl;
                #pragma unroll
                for (int i = 0; i < 4; ++i) {
                    int row = lk * 4 + i;
                    float t = fmaxf(fmaf(c1[ctl][i], sA[ct], sB[ct]), 0.f);
                    unsigned u = __builtin_bit_cast(unsigned, t);
                    unsigned hi = u >> 16;
                    unsigned lo = (unsigned)(unsigned short)f2bf(t - __builtin_bit_cast(float, u & 0xFFFF0000u));
                    int col = ctl * 16 + lr;
                    tw[row * 32 + ((((col >> 2) ^ (row & 7)) << 2) | (col & 3))] = (lo << 16) | hi;
                }
            }

            // A2-frags from chunk: row = lr, k = lk*8 .. +7
            u32x4 W0 = *(const u32x4*)&tw[lr * 32 + (((2 * lk) ^ (lr & 7)) << 2)];
            u32x4 W1v = *(const u32x4*)&tw[lr * 32 + (((2 * lk + 1) ^ (lr & 7)) << 2)];
            u32x4 hv, lv;
            hv.x = __builtin_amdgcn_perm(W0.y, W0.x, 0x05040100u);
            hv.y = __builtin_amdgcn_perm(W0.w, W0.z, 0x05040100u);
            hv.z = __builtin_amdgcn_perm(W1v.y, W1v.x, 0x05040100u);
            hv.w = __builtin_amdgcn_perm(W1v.w, W1v.z, 0x05040100u);
            lv.x = __builtin_amdgcn_perm(W0.y, W0.x, 0x07060302u);
            lv.y = __builtin_amdgcn_perm(W0.w, W0.z, 0x07060302u);
            lv.z = __builtin_amdgcn_perm(W1v.y, W1v.x, 0x07060302u);
            lv.w = __builtin_amdgcn_perm(W1v.w, W1v.z, 0x07060302u);
            bf16x8 a2h = __builtin_bit_cast(bf16x8, hv);
            bf16x8 a2l = __builtin_bit_cast(bf16x8, lv);

            // GEMM2 partial: h-units ks2*4+lk, bf16x3
            #pragma unroll
            for (int ct = 0; ct < 8; ++ct) {
                int r = ct * 16 + lr;
                int off = r * 128 + (((ks2 * 4 + lk) ^ (r & 7)) << 3);
                bf16x8 bh = *(const bf16x8*)&Wl[32768 + off];    // W2hi
                bf16x8 bl = *(const bf16x8*)&Wl[49152 + off];    // W2lo
                acc2[ct] = __builtin_amdgcn_mfma_f32_16x16x32_bf16(a2h, bh, acc2[ct], 0, 0, 0);
                acc2[ct] = __builtin_amdgcn_mfma_f32_16x16x32_bf16(a2l, bh, acc2[ct], 0, 0, 0);
                acc2[ct] = __builtin_amdgcn_mfma_f32_16x16x32_bf16(a2h, bl, acc2[ct], 0, 0, 0);
            }
        }

        // ---- bias + ReLU, store ----
        #pragma unroll
        for (int ct = 0; ct < 8; ++ct) {
            int hid = ct * 16 + lr;
            #pragma unroll
            for (int i = 0; i < 4; ++i) {
                long node = (long)tile * 128 + w * 16 + lk * 4 + i;
                if (node < N_NODES)
                    out[node * CH + hid] = fmaxf(acc2[ct][i] + b2c[ct], 0.f);
            }
        }
    }
}

__global__ void init_out(float* __restrict__ out, const float* __restrict__ lin_b) {
    int i = blockIdx.x * blockDim.x + threadIdx.x;
    if (i < N_GRAPHS) out[i] = lin_b[0];
}

// out[batch[n]] += dot(h[n], lin_w); one wave per node
__global__ __launch_bounds__(256) void pool_kernel(
    const float* __restrict__ h, const int* __restrict__ batch,
    const float* __restrict__ lin_w, float* __restrict__ out)
{
    int gid = blockIdx.x * blockDim.x + threadIdx.x;
    int n = gid >> 6;
    int lane = gid & 63;
    if (n >= N_NODES) return;
    float2 v = ((const float2*)(h + (long)n * CH))[lane];
    float2 w = ((const float2*)lin_w)[lane];
    float s = v.x * w.x + v.y * w.y;
    #pragma unroll
    for (int off = 32; off > 0; off >>= 1) s += __shfl_down(s, off);
    if (lane == 0) atomicAdd(&out[batch[n]], s);
}

extern "C" void kernel_launch(void* const* d_in, const int* in_sizes, int n_in,
                              void* d_out, int out_size, void* d_ws, size_t ws_size,
                              hipStream_t stream) {
    const float* x     = (const float*)d_in[0];
    const int*   ei    = (const int*)d_in[1];
    const int*   batch = (const int*)d_in[2];
    const float* lin_w = (const float*)d_in[3];
    const float* lin_b = (const float*)d_in[4];
    const float* P[3][8];
    for (int l = 0; l < 3; ++l)
        for (int j = 0; j < 8; ++j)
            P[l][j] = (const float*)d_in[5 + l * 8 + j];
    // P[l]: 0=w1 1=b1 2=gamma 3=beta 4=mean 5=var 6=w2 7=b2

    const int* src = ei;            // edge_index[0]
    const int* dst = ei + N_EDGES;  // edge_index[1]

    // workspace layout
    float* buf0 = (float*)d_ws;
    float* buf1 = buf0 + (size_t)N_NODES * CH;
    int* deg       = (int*)(buf1 + (size_t)N_NODES * CH);
    int* row_start = deg + N_NODES;
    int* adj       = row_start + N_NODES + 1;
    int* partial   = adj + N_EDGES;
    short* wts = (short*)(((uintptr_t)(partial + SCAN_NB) + 255) & ~(uintptr_t)255);
    short* wg[3];
    float* bnA[3]; float* bnB[3];
    {
        short* p = wts;
        for (int l = 0; l < 3; ++l) {
            wg[l] = p; p += 65536;          // 4 planes x 16384 shorts
            bnA[l] = (float*)p; p += 256;   // 128 floats each
            bnB[l] = (float*)p; p += 256;
        }
    }

    // ---- weight prep ----
    for (int l = 0; l < 3; ++l)
        prep_kernel<<<128, 256, 0, stream>>>(
            P[l][0], P[l][6], P[l][1], P[l][2], P[l][3], P[l][4], P[l][5],
            wg[l], bnA[l], bnB[l]);

    // ---- CSR build ----
    hipMemsetAsync(deg, 0, N_NODES * sizeof(int), stream);
    count_kernel<<<(N_EDGES + 255) / 256, 256, 0, stream>>>(dst, deg);
    block_sums_kernel<<<SCAN_NB, 256, 0, stream>>>(deg, partial);
    scan_partial_kernel<<<1, 64, 0, stream>>>(partial);
    scan_final_kernel<<<SCAN_NB, 256, 0, stream>>>(deg, partial, row_start);
    hipMemsetAsync(deg, 0, N_NODES * sizeof(int), stream);  // reuse as cursor
    fill_kernel<<<(N_EDGES + 255) / 256, 256, 0, stream>>>(src, dst, row_start, deg, adj);

    // ---- 3 fused GIN layers (gather + MLP), ping-pong ----
    gin_layer<<<GRID, THREADS, 0, stream>>>(x,    buf0, row_start, adj, wg[0], bnA[0], bnB[0], P[0][7]);
    gin_layer<<<GRID, THREADS, 0, stream>>>(buf0, buf1, row_start, adj, wg[1], bnA[1], bnB[1], P[1][7]);
    gin_layer<<<GRID, THREADS, 0, stream>>>(buf1, buf0, row_start, adj, wg[2], bnA[2], bnB[2], P[2][7]);

    // ---- pool + final linear (OUT_CH == 1) ----
    init_out<<<(N_GRAPHS + 255) / 256, 256, 0, stream>>>((float*)d_out, lin_b);
    pool_kernel<<<(N_NODES * 64) / 256, 256, 0, stream>>>(buf0, batch, lin_w, (float*)d_out);
}